// Round 6
// baseline (138.903 us; speedup 1.0000x reference)
//
#include <hip/hip_runtime.h>
#include <stdint.h>

// VectorQuantizer on MI355X (gfx950), fp32 exact path, round 6.
// Round-5 diagnosis: ds_read(x) + s_load(w) share lgkmcnt; SMEM is
// out-of-order so every x-read dependency forces lgkmcnt(0), draining w
// prefetches -> VALUBusy 50%. Round 4 proved global x (vmcnt) + scalar w
// (lgkmcnt) pipeline independently (64% busy). This round: round-5 blocking
// (64 pts x all 512 codes per block, in-LDS argmin merge, fused epilogue)
// with x streamed from a transposed global xT staged in ws. acc[32] (K
// blocked by 32) halves x-reload traffic; unified VGPR/AGPR file absorbs it
// (round-5 showed VGPR=20 with 16 acc live).
// Fallback: if ws_size can't hold xT, run the round-5 kernel unchanged.

#define N_PTS 65536
#define DDIM 64
#define KCODES 512

// ws layout (big path): xT 16777216 B @ 0, wT 131072 B @ 16777216,
//                       wsq 2048 B @ 16908288   -> need 16910336 B
// ws layout (fallback): wT 131072 B @ 0, wsq 2048 B @ 131072

// ---------------- big-ws path ----------------

__global__ void vq_prep2(const float* __restrict__ x_in,
                         const float* __restrict__ w,
                         float* __restrict__ xT,   // [64][65536] in ws
                         float* __restrict__ wT, float* __restrict__ wsq,
                         float* __restrict__ loss_out) {
  __shared__ float tile[64][65];
  const int b = blockIdx.x;
  const int t = threadIdx.x;
  if (b < 1024) {
    // transpose a 64-point x tile: x[n0+r][d] -> xT[d][n0+r]
    const float4* src = (const float4*)(x_in + (size_t)b * 4096);
#pragma unroll
    for (int p = 0; p < 4; ++p) {
      int e = p * 1024 + t * 4;
      float4 v = src[p * 256 + t];          // coalesced 16B
      int r = e >> 6, c = e & 63;
      tile[r][c] = v.x; tile[r][c + 1] = v.y;
      tile[r][c + 2] = v.z; tile[r][c + 3] = v.w;
    }
    __syncthreads();
#pragma unroll
    for (int p = 0; p < 4; ++p) {
      int e = p * 1024 + t * 4;
      int d = e >> 6, c = e & 63;
      float4 v = make_float4(tile[c][d], tile[c + 1][d],
                             tile[c + 2][d], tile[c + 3][d]);
      *(float4*)(xT + (size_t)d * N_PTS + (size_t)b * 64 + c) = v;  // coalesced
    }
  } else {
    int g = (b - 1024) * 256 + t;  // 0..32767 over D*K
    int d = g >> 9, k = g & 511;
    wT[k * DDIM + d] = w[g];
    if (g < KCODES) {
      float s = 0.f;
      for (int dd = 0; dd < DDIM; ++dd) {
        float tv = w[dd * KCODES + g];
        s = fmaf(tv, tv, s);
      }
      wsq[g] = s;
    }
    if (g == 0) *loss_out = 0.f;
  }
}

__global__ __launch_bounds__(256, 4)
void vq_main2(const float* __restrict__ xT, const float* __restrict__ w,
              const float* __restrict__ wT, const float* __restrict__ wsq,
              float* __restrict__ out_q, float* __restrict__ out_idx,
              float* __restrict__ loss_out) {
  __shared__ unsigned long long sm_key[256];
  __shared__ unsigned int sm_idx[64];
  __shared__ float sm_loss[64];

  const int t = threadIdx.x;
  const int pb = blockIdx.x;   // 1024 blocks, 64 points each
  // quarter id is wave-uniform; readfirstlane pins it to an SGPR so all
  // w/wsq addressing stays scalar -> s_load promotion (rounds 4/5 proven).
  const int q = __builtin_amdgcn_readfirstlane(t >> 6);
  const int pt = t & 63;
  const int n = (pb << 6) | pt;            // global point id
  const int kq = q << 7;                   // this wave's 128-code range

  float best = 3.0e38f;
  int bidx = 0;
  float sx = 0.f;

  const float* xp = xT + n;                // + d*65536 per dim (int offsets)

#pragma unroll 1
  for (int kb2 = 0; kb2 < 4; ++kb2) {      // 32 codes per iteration
    const int k0 = kq + (kb2 << 5);
    const float* wp = w + k0;              // scalar base
    float acc[32];
#pragma unroll
    for (int c = 0; c < 32; ++c) acc[c] = 0.f;
#pragma unroll 1
    for (int d8 = 0; d8 < 8; ++d8) {
      float xv[8];
#pragma unroll
      for (int dd = 0; dd < 8; ++dd)
        xv[dd] = xp[((d8 << 3) + dd) << 16];   // global b32, coalesced, vmcnt
      if (q == 0 && kb2 == 0) {  // uniform branch: ||x||^2 once per point
#pragma unroll
        for (int dd = 0; dd < 8; ++dd) sx = fmaf(xv[dd], xv[dd], sx);
      }
#pragma unroll
      for (int dd = 0; dd < 8; ++dd) {
        const float* wd = wp + (((d8 << 3) + dd) << 9);
#pragma unroll
        for (int c = 0; c < 32; ++c)
          acc[c] = fmaf(wd[c], xv[dd], acc[c]);  // sgpr * vgpr fmac
      }
    }
#pragma unroll
    for (int c = 0; c < 32; ++c) {
      float dist = fmaf(acc[c], -2.0f, wsq[k0 + c]);
      if (dist < best) { best = dist; bidx = k0 + c; }  // strict <: first-min
    }
  }

  // sortable-float pack, idx in low bits -> exact ties pick lowest index
  unsigned int ub = __float_as_uint(best);
  ub = (ub & 0x80000000u) ? ~ub : (ub | 0x80000000u);
  sm_key[(q << 6) | pt] =
      ((unsigned long long)ub << 32) | (unsigned long long)(unsigned int)bidx;
  __syncthreads();

  if (t < 64) {  // q==0 threads own sx
    unsigned long long k = sm_key[t];
    unsigned long long k1 = sm_key[64 + t];
    unsigned long long k2 = sm_key[128 + t];
    unsigned long long k3 = sm_key[192 + t];
    k = k1 < k ? k1 : k;
    k = k2 < k ? k2 : k;
    k = k3 < k ? k3 : k;
    unsigned int idx = (unsigned int)k;
    sm_idx[t] = idx;
    out_idx[(size_t)pb * 64 + t] = (float)idx;
    unsigned int u = (unsigned int)(k >> 32);
    u = (u & 0x80000000u) ? (u & 0x7FFFFFFFu) : ~u;
    sm_loss[t] = (__uint_as_float(u) + sx) * (1.25f / 4194304.0f);
  }
  __syncthreads();

  float4* dst = (float4*)(out_q + (size_t)pb * 4096);
#pragma unroll
  for (int i = 0; i < 4; ++i) {
    int e = (i * 256 + t) * 4;
    int p2 = e >> 6, d = e & 63;
    unsigned int idx = sm_idx[p2];
    float4 v = *(const float4*)(wT + (size_t)idx * DDIM + d);  // L2-hot
    dst[i * 256 + t] = v;  // coalesced
  }

  if (t == 0) {
    float s = 0.f;
#pragma unroll
    for (int i = 0; i < 64; ++i) s += sm_loss[i];
    atomicAdd(loss_out, s);  // 1024 adds total
  }
}

// ---------------- fallback path (round-5 kernel, proven 70us) ----------------

__global__ void vq_prep(const float* __restrict__ w, float* __restrict__ wT,
                        float* __restrict__ wsq, float* __restrict__ loss_out) {
  int g = blockIdx.x * 256 + threadIdx.x;
  int d = g >> 9, k = g & 511;
  wT[k * DDIM + d] = w[g];
  if (g < KCODES) {
    float s = 0.f;
    for (int dd = 0; dd < DDIM; ++dd) {
      float t = w[dd * KCODES + g];
      s = fmaf(t, t, s);
    }
    wsq[g] = s;
  }
  if (g == 0) *loss_out = 0.f;
}

__global__ __launch_bounds__(256, 4)
void vq_main(const float* __restrict__ x_in, const float* __restrict__ w,
             const float* __restrict__ wT, const float* __restrict__ wsq,
             float* __restrict__ out_q, float* __restrict__ out_idx,
             float* __restrict__ loss_out) {
  __shared__ float xs[DDIM][65];
  __shared__ unsigned long long sm_key[4 * 64];
  __shared__ unsigned int sm_idx[64];
  __shared__ float sm_loss[64];

  const int t = threadIdx.x;
  const int pb = blockIdx.x;
  {
    const float4* src = (const float4*)(x_in + (size_t)pb * 4096);
#pragma unroll
    for (int i = 0; i < 4; ++i) {
      float4 v = src[i * 256 + t];
      int e = (i * 256 + t) * 4;
      int pt = e >> 6, d = e & 63;
      xs[d][pt] = v.x; xs[d + 1][pt] = v.y;
      xs[d + 2][pt] = v.z; xs[d + 3][pt] = v.w;
    }
  }
  __syncthreads();

  const int q = __builtin_amdgcn_readfirstlane(t >> 6);
  const int pt = t & 63;
  const int kq = q << 7;

  float best = 3.0e38f;
  int bidx = 0;
  float sx = 0.f;

#pragma unroll 1
  for (int kb = 0; kb < 8; ++kb) {
    const int k0 = kq + (kb << 4);
    const float* wp = w + k0;
    float acc[16];
#pragma unroll
    for (int c = 0; c < 16; ++c) acc[c] = 0.f;
#pragma unroll 1
    for (int d8 = 0; d8 < 8; ++d8) {
      float xv[8];
#pragma unroll
      for (int dd = 0; dd < 8; ++dd) xv[dd] = xs[d8 * 8 + dd][pt];
      if (q == 0 && kb == 0) {
#pragma unroll
        for (int dd = 0; dd < 8; ++dd) sx = fmaf(xv[dd], xv[dd], sx);
      }
#pragma unroll
      for (int dd = 0; dd < 8; ++dd) {
        const float* wd = wp + (size_t)(d8 * 8 + dd) * KCODES;
#pragma unroll
        for (int c = 0; c < 16; ++c)
          acc[c] = fmaf(wd[c], xv[dd], acc[c]);
      }
    }
#pragma unroll
    for (int c = 0; c < 16; ++c) {
      float dist = fmaf(acc[c], -2.0f, wsq[k0 + c]);
      if (dist < best) { best = dist; bidx = k0 + c; }
    }
  }

  unsigned int ub = __float_as_uint(best);
  ub = (ub & 0x80000000u) ? ~ub : (ub | 0x80000000u);
  sm_key[(q << 6) | pt] =
      ((unsigned long long)ub << 32) | (unsigned long long)(unsigned int)bidx;
  __syncthreads();

  if (t < 64) {
    unsigned long long k = sm_key[t];
    unsigned long long k1 = sm_key[64 + t];
    unsigned long long k2 = sm_key[128 + t];
    unsigned long long k3 = sm_key[192 + t];
    k = k1 < k ? k1 : k;
    k = k2 < k ? k2 : k;
    k = k3 < k ? k3 : k;
    unsigned int idx = (unsigned int)k;
    sm_idx[t] = idx;
    out_idx[(size_t)pb * 64 + t] = (float)idx;
    unsigned int u = (unsigned int)(k >> 32);
    u = (u & 0x80000000u) ? (u & 0x7FFFFFFFu) : ~u;
    sm_loss[t] = (__uint_as_float(u) + sx) * (1.25f / 4194304.0f);
  }
  __syncthreads();

  float4* dst = (float4*)(out_q + (size_t)pb * 4096);
#pragma unroll
  for (int i = 0; i < 4; ++i) {
    int e = (i * 256 + t) * 4;
    int p2 = e >> 6, d = e & 63;
    unsigned int idx = sm_idx[p2];
    float4 v = *(const float4*)(wT + (size_t)idx * DDIM + d);
    dst[i * 256 + t] = v;
  }

  if (t == 0) {
    float s = 0.f;
#pragma unroll
    for (int i = 0; i < 64; ++i) s += sm_loss[i];
    atomicAdd(loss_out, s);
  }
}

extern "C" void kernel_launch(void* const* d_in, const int* in_sizes, int n_in,
                              void* d_out, int out_size, void* d_ws, size_t ws_size,
                              hipStream_t stream) {
  const float* x = (const float*)d_in[0];  // (64,32,32,64) fp32
  const float* w = (const float*)d_in[1];  // (64,512) fp32

  float* out_q = (float*)d_out;            // 4194304 floats
  float* out_idx = out_q + 4194304;        // 65536 floats (indices)
  float* loss_out = out_q + 4259840;       // 1 float

  char* ws = (char*)d_ws;
  if (ws_size >= 16910336) {
    float* xT = (float*)(ws);
    float* wT = (float*)(ws + 16777216);
    float* wsq = (float*)(ws + 16908288);
    vq_prep2<<<1152, 256, 0, stream>>>(x, w, xT, wT, wsq, loss_out);
    vq_main2<<<1024, 256, 0, stream>>>(xT, w, wT, wsq, out_q, out_idx,
                                       loss_out);
  } else {
    float* wT = (float*)(ws);
    float* wsq = (float*)(ws + 131072);
    vq_prep<<<128, 256, 0, stream>>>(w, wT, wsq, loss_out);
    vq_main<<<1024, 256, 0, stream>>>(x, w, wT, wsq, out_q, out_idx,
                                      loss_out);
  }
}